// Round 1
// 154.128 us; speedup vs baseline: 1.0413x; 1.0413x over previous
//
#include <hip/hip_runtime.h>
#include <stdint.h>

typedef unsigned short u16;
typedef unsigned int u32;
typedef short bf16x8 __attribute__((ext_vector_type(8)));
typedef float f32x4 __attribute__((ext_vector_type(4)));
typedef float f32x16 __attribute__((ext_vector_type(16)));

#define K_DIM 512

__device__ __forceinline__ u16 f2bf(float f) {
  union { float f; u32 u; } v; v.f = f;
  return (u16)((v.u + 0x8000u) >> 16);  // round-half-up
}
__device__ __forceinline__ u32 pk2(float lo, float hi) {
  union { float f; u32 u; } a, b; a.f = lo; b.f = hi;
  return __builtin_amdgcn_perm(b.u + 0x8000u, a.u + 0x8000u, 0x07060302u);
}

// ---------------- kernel 0: fp32 -> bf16 conversions ----------------
__global__ void cvt_kernel(const float* __restrict__ x1, const float* __restrict__ x2,
                           const float* __restrict__ qkvw, const float* __restrict__ outw,
                           u16* __restrict__ xb, u16* __restrict__ wqkv, u16* __restrict__ wout) {
  int tid = blockIdx.x * 256 + threadIdx.x;
  const float4* src; u16* dst; int idx = tid;
  if (idx < 524288)        { src = (const float4*)x1;   dst = xb; }
  else if (idx < 1048576)  { src = (const float4*)x2;   dst = xb + 2097152; idx -= 524288; }
  else if (idx < 1245184)  { src = (const float4*)qkvw; dst = wqkv;         idx -= 1048576; }
  else                     { src = (const float4*)outw; dst = wout;         idx -= 1245184; }
  float4 v = src[idx];
  *(uint2*)&dst[idx * 4] = make_uint2(pk2(v.x, v.y), pk2(v.z, v.w));
}

#define LDA 40  // BK=32 + 8 pad

// ---------------- kernel 1: QKV GEMM (C^T, dbuf single-barrier) + scatter epilogue ----------------
__global__ __launch_bounds__(256, 3) void qkv_gemm(
    const u16* __restrict__ A, const u16* __restrict__ W, const float* __restrict__ bias,
    u16* __restrict__ qb, u16* __restrict__ kb, u16* __restrict__ vtb) {
  __shared__ __align__(16) u16 As[2][128 * LDA];
  __shared__ __align__(16) u16 Bs[2][128 * LDA];
  const int t = threadIdx.x;
  const int m0 = blockIdx.x * 128, n0 = blockIdx.y * 128;
  const int lane = t & 63, l16 = lane & 15, quad = lane >> 4;
  const int w = t >> 6;
  const int wm = (w >> 1) * 64, wn = (w & 1) * 64;
  const int sr = t >> 2, sc = (t & 3) * 8;

  const u16* Ap = A + (size_t)(m0 + sr) * K_DIM + sc;
  const u16* Wp = W + (size_t)(n0 + sr) * K_DIM + sc;

  f32x4 acc[4][4];
#pragma unroll
  for (int i = 0; i < 4; ++i)
#pragma unroll
    for (int j = 0; j < 4; ++j) acc[i][j] = (f32x4){0.f, 0.f, 0.f, 0.f};

  uint4 ra0 = *(const uint4*)(Ap);
  uint4 ra1 = *(const uint4*)(Ap + 64 * K_DIM);
  uint4 rb0 = *(const uint4*)(Wp);
  uint4 rb1 = *(const uint4*)(Wp + 64 * K_DIM);
  *(uint4*)&As[0][sr * LDA + sc] = ra0;
  *(uint4*)&As[0][(sr + 64) * LDA + sc] = ra1;
  *(uint4*)&Bs[0][sr * LDA + sc] = rb0;
  *(uint4*)&Bs[0][(sr + 64) * LDA + sc] = rb1;
  ra0 = *(const uint4*)(Ap + 32);
  ra1 = *(const uint4*)(Ap + 64 * K_DIM + 32);
  rb0 = *(const uint4*)(Wp + 32);
  rb1 = *(const uint4*)(Wp + 64 * K_DIM + 32);
  __syncthreads();

  for (int kt = 0; kt < 16; ++kt) {
    const int cur = kt & 1, nxt = cur ^ 1;
    if (kt < 15) {
      *(uint4*)&As[nxt][sr * LDA + sc] = ra0;
      *(uint4*)&As[nxt][(sr + 64) * LDA + sc] = ra1;
      *(uint4*)&Bs[nxt][sr * LDA + sc] = rb0;
      *(uint4*)&Bs[nxt][(sr + 64) * LDA + sc] = rb1;
    }
    if (kt < 14) {
      int ko = (kt + 2) * 32;
      ra0 = *(const uint4*)(Ap + ko);
      ra1 = *(const uint4*)(Ap + 64 * K_DIM + ko);
      rb0 = *(const uint4*)(Wp + ko);
      rb1 = *(const uint4*)(Wp + 64 * K_DIM + ko);
    }
    bf16x8 af[4], bfr[4];
#pragma unroll
    for (int mi = 0; mi < 4; ++mi)
      af[mi] = *(const bf16x8*)&As[cur][(wm + mi * 16 + l16) * LDA + quad * 8];
#pragma unroll
    for (int ni = 0; ni < 4; ++ni)
      bfr[ni] = *(const bf16x8*)&Bs[cur][(wn + ni * 16 + l16) * LDA + quad * 8];
#pragma unroll
    for (int mi = 0; mi < 4; ++mi)
#pragma unroll
      for (int ni = 0; ni < 4; ++ni)
        acc[mi][ni] = __builtin_amdgcn_mfma_f32_16x16x32_bf16(bfr[ni], af[mi], acc[mi][ni], 0, 0, 0);
    __syncthreads();
  }

  const int fbase = n0 + wn;
  const int h = fbase / 192;
  const int s = (fbase - h * 192) >> 6;
  float4 bv[4];
#pragma unroll
  for (int ni = 0; ni < 4; ++ni)
    bv[ni] = *(const float4*)&bias[fbase + ni * 16 + quad * 4];
  const int bh = m0 >> 11;
  const int lbase = (m0 & 2047) + wm;

  if (s == 2) {
    u16* dst = vtb + (size_t)((bh * 8 + h) * 64) * 2048;
#pragma unroll
    for (int mi = 0; mi < 4; ++mi) {
      int l = lbase + mi * 16 + l16;
#pragma unroll
      for (int ni = 0; ni < 4; ++ni)
#pragma unroll
        for (int r = 0; r < 4; ++r)
          dst[(ni * 16 + quad * 4 + r) * 2048 + l] = f2bf(acc[mi][ni][r] + bv[ni][r]);
    }
  } else {
    u16* dst = (s == 0 ? qb : kb) + (size_t)((bh * 8 + h) * 2048) * 64;
    const float sc2 = (s == 0) ? 0.18033688011112042f : 1.0f;
#pragma unroll
    for (int mi = 0; mi < 4; ++mi) {
      int l = lbase + mi * 16 + l16;
#pragma unroll
      for (int ni = 0; ni < 4; ++ni) {
        float v0 = (acc[mi][ni][0] + bv[ni][0]) * sc2;
        float v1 = (acc[mi][ni][1] + bv[ni][1]) * sc2;
        float v2 = (acc[mi][ni][2] + bv[ni][2]) * sc2;
        float v3 = (acc[mi][ni][3] + bv[ni][3]) * sc2;
        *(uint2*)&dst[(size_t)l * 64 + ni * 16 + quad * 4] = make_uint2(pk2(v0, v1), pk2(v2, v3));
      }
    }
  }
}

// ---------------- kernel 2: flash cross-attention (S^T, 32x32x16 MFMA) ----------------
// grid 512: 128 q-rows/block, 4 waves x 32 q-rows (32x32 tiles); K-tiles of 64.
// This version: P kept IN REGISTERS (T12: pk2 + v_permlane32_swap_b32), K/V double-buffered
// in LDS with ONE barrier per K-tile (classic dbuf: buffer written in kt was last read in
// kt-1, barrier at end of kt-1 guarantees all waves done). Q frags read directly from global
// (once per wave, L2-resident) -- no Q/P LDS at all.
// Layouts (m101-verified 32x32x16): C/D col=lane&31, row=(reg&3)+8*(reg>>2)+4*(lane>>5);
// sacc[mi][r] = S^T[kcol=(r&3)+8*(r>>2)+4*h2+32*mi][qrow=l32].
// PV B-frag at step ks needs P[kcol=ks*16+h2*8+j][qrow=l32]: 2 permlane32_swaps per frag
// (first.hi <-> second.lo): swap(pk(p0,p1), pk(p4,p5)) -> word0 / word2 for BOTH halves.
#define LQ 72

__global__ __launch_bounds__(256, 2) void attn_kernel(
    const u16* __restrict__ qb, const u16* __restrict__ kb, const u16* __restrict__ vtb,
    u16* __restrict__ attnb) {
  __shared__ __align__(16) u16 Ks[2][64 * LQ];    // [buf][kcol][d]
  __shared__ __align__(16) u16 VTs[2][64 * LQ];   // [buf][d][kcol]

  const int t = threadIdx.x;
  const int w = t >> 6, lane = t & 63, l32 = lane & 31, h2 = lane >> 5;
  const int bid = blockIdx.x;
  const int comb = bid & 31;        // XCD swizzle: same comb -> same bid%8 -> same XCD
  const int qt = bid >> 5;
  const int h = comb & 7, bb = (comb >> 3) & 1, pair = comb >> 4;
  const int in_q = pair, in_kv = pair ^ 1;

  const u16* Qg = qb + (size_t)((in_q * 2 + bb) * 8 + h) * 2048 * 64;
  const u16* Kg = kb + (size_t)((in_kv * 2 + bb) * 8 + h) * 2048 * 64;
  const u16* Vg = vtb + (size_t)((in_kv * 2 + bb) * 8 + h) * 64 * 2048;

  // K/V tile 0 -> regs -> LDS buf0; prefetch tile 1 into regs
  const int srow = t >> 3, sseg = (t & 7) * 8;   // rows 0..31 (+32)
  uint4 rk0 = *(const uint4*)(Kg + srow * 64 + sseg);
  uint4 rk1 = *(const uint4*)(Kg + (srow + 32) * 64 + sseg);
  uint4 rv0 = *(const uint4*)(Vg + srow * 2048 + sseg);
  uint4 rv1 = *(const uint4*)(Vg + (srow + 32) * 2048 + sseg);

  // Q fragments straight from global (16B aligned, read once)
  bf16x8 qf[4];
#pragma unroll
  for (int ks = 0; ks < 4; ++ks)
    qf[ks] = *(const bf16x8*)(Qg + (qt * 128 + w * 32 + l32) * 64 + ks * 16 + h2 * 8);

  *(uint4*)&Ks[0][srow * LQ + sseg] = rk0;
  *(uint4*)&Ks[0][(srow + 32) * LQ + sseg] = rk1;
  *(uint4*)&VTs[0][srow * LQ + sseg] = rv0;
  *(uint4*)&VTs[0][(srow + 32) * LQ + sseg] = rv1;
  rk0 = *(const uint4*)(Kg + (64 + srow) * 64 + sseg);
  rk1 = *(const uint4*)(Kg + (64 + srow + 32) * 64 + sseg);
  rv0 = *(const uint4*)(Vg + srow * 2048 + 64 + sseg);
  rv1 = *(const uint4*)(Vg + (srow + 32) * 2048 + 64 + sseg);
  __syncthreads();   // tile 0 visible

  f32x16 oacc[2];
#pragma unroll
  for (int mi = 0; mi < 2; ++mi)
#pragma unroll
    for (int r = 0; r < 16; ++r) oacc[mi][r] = 0.f;
  float rs = 0.f;

#pragma unroll 2
  for (int kt = 0; kt < 32; ++kt) {
    const int cur = kt & 1, nxt = cur ^ 1;

    // S^T[kcol 64][qrow 32] = K (A) . Q (B): 2 m-tiles x 4 k-steps
    f32x16 sacc[2];
#pragma unroll
    for (int mi = 0; mi < 2; ++mi)
#pragma unroll
      for (int r = 0; r < 16; ++r) sacc[mi][r] = 0.f;
#pragma unroll
    for (int ks = 0; ks < 4; ++ks) {
      bf16x8 kfr0 = *(const bf16x8*)&Ks[cur][l32 * LQ + ks * 16 + h2 * 8];
      bf16x8 kfr1 = *(const bf16x8*)&Ks[cur][(32 + l32) * LQ + ks * 16 + h2 * 8];
      sacc[0] = __builtin_amdgcn_mfma_f32_32x32x16_bf16(kfr0, qf[ks], sacc[0], 0, 0, 0);
      sacc[1] = __builtin_amdgcn_mfma_f32_32x32x16_bf16(kfr1, qf[ks], sacc[1], 0, 0, 0);
    }

    // p = exp2(s); pack to bf16 and redistribute across lane halves IN REGISTERS.
    // mi covers kcols 32*mi..32*mi+31 -> pf[mi*2] (ks=2mi), pf[mi*2+1] (ks=2mi+1).
    bf16x8 pf[4];
#pragma unroll
    for (int mi = 0; mi < 2; ++mi) {
      float p[16];
#pragma unroll
      for (int r = 0; r < 16; ++r) p[r] = __builtin_amdgcn_exp2f(sacc[mi][r]);
#pragma unroll
      for (int r = 0; r < 16; r += 4) rs += (p[r] + p[r + 1]) + (p[r + 2] + p[r + 3]);
      u32 a0 = pk2(p[0], p[1]),   b0 = pk2(p[2], p[3]);      // kc 4h2+{0,1},{2,3}
      u32 c0 = pk2(p[4], p[5]),   d0 = pk2(p[6], p[7]);      // kc 8+4h2+{0,1},{2,3}
      u32 a1 = pk2(p[8], p[9]),   b1 = pk2(p[10], p[11]);    // kc 16+4h2+...
      u32 c1 = pk2(p[12], p[13]), d1 = pk2(p[14], p[15]);    // kc 24+4h2+...
      // swap first.hi <-> second.lo: a0 -> frag word0 (both halves), c0 -> word2
      asm("v_permlane32_swap_b32 %0, %1" : "+v"(a0), "+v"(c0));
      asm("v_permlane32_swap_b32 %0, %1" : "+v"(b0), "+v"(d0));
      asm("v_permlane32_swap_b32 %0, %1" : "+v"(a1), "+v"(c1));
      asm("v_permlane32_swap_b32 %0, %1" : "+v"(b1), "+v"(d1));
      union { u32 u[4]; bf16x8 v; } f0, f1;
      f0.u[0] = a0; f0.u[1] = b0; f0.u[2] = c0; f0.u[3] = d0;
      f1.u[0] = a1; f1.u[1] = b1; f1.u[2] = c1; f1.u[3] = d1;
      pf[mi * 2] = f0.v;
      pf[mi * 2 + 1] = f1.v;
    }

    // stage next K/V tile (buf[nxt] last read in kt-1; safe after that barrier) and
    // issue global loads for tile kt+2 -- latency spans PV + barrier + next S.
    if (kt < 31) {
      *(uint4*)&Ks[nxt][srow * LQ + sseg] = rk0;
      *(uint4*)&Ks[nxt][(srow + 32) * LQ + sseg] = rk1;
      *(uint4*)&VTs[nxt][srow * LQ + sseg] = rv0;
      *(uint4*)&VTs[nxt][(srow + 32) * LQ + sseg] = rv1;
      if (kt < 30) {
        const int ko = (kt + 2) * 64;
        rk0 = *(const uint4*)(Kg + (ko + srow) * 64 + sseg);
        rk1 = *(const uint4*)(Kg + (ko + srow + 32) * 64 + sseg);
        rv0 = *(const uint4*)(Vg + srow * 2048 + ko + sseg);
        rv1 = *(const uint4*)(Vg + (srow + 32) * 2048 + ko + sseg);
      }
    }

    // O^T[d 64][qrow 32] += V^T (A) . P (B)
#pragma unroll
    for (int ks = 0; ks < 4; ++ks) {
      bf16x8 vf0 = *(const bf16x8*)&VTs[cur][l32 * LQ + ks * 16 + h2 * 8];
      bf16x8 vf1 = *(const bf16x8*)&VTs[cur][(32 + l32) * LQ + ks * 16 + h2 * 8];
      oacc[0] = __builtin_amdgcn_mfma_f32_32x32x16_bf16(vf0, pf[ks], oacc[0], 0, 0, 0);
      oacc[1] = __builtin_amdgcn_mfma_f32_32x32x16_bf16(vf1, pf[ks], oacc[1], 0, 0, 0);
    }
    if (kt < 31) __syncthreads();   // single barrier per K-tile (dbuf)
  }

  // epilogue: qrow = w*32 + l32 owned by lanes (l32, l32+32) with complementary kcol/d sets
  rs += __shfl_xor(rs, 32);
  const float inv = 1.0f / rs;
  const int row = in_q * 4096 + bb * 2048 + qt * 128 + w * 32 + l32;
#pragma unroll
  for (int mi = 0; mi < 2; ++mi)
#pragma unroll
    for (int rg = 0; rg < 4; ++rg) {
      float v0 = oacc[mi][rg * 4 + 0] * inv;
      float v1 = oacc[mi][rg * 4 + 1] * inv;
      float v2 = oacc[mi][rg * 4 + 2] * inv;
      float v3 = oacc[mi][rg * 4 + 3] * inv;
      *(uint2*)&attnb[(size_t)row * 512 + h * 64 + mi * 32 + rg * 8 + h2 * 4] =
          make_uint2(pk2(v0, v1), pk2(v2, v3));
    }
}

// ---------------- kernel 3: output projection (64x128 tiles, dbuf) ----------------
__global__ __launch_bounds__(256, 2) void out_gemm(
    const u16* __restrict__ A, const u16* __restrict__ W, const float* __restrict__ bias,
    float* __restrict__ out) {
  __shared__ __align__(16) u16 As[2][64 * LDA];
  __shared__ __align__(16) u16 Bs[2][128 * LDA];
  const int t = threadIdx.x;
  const int m0 = blockIdx.x * 64, n0 = blockIdx.y * 128;
  const int lane = t & 63, l16 = lane & 15, quad = lane >> 4;
  const int w = t >> 6;
  const int wm = (w & 1) * 32, wn = (w >> 1) * 64;
  const int ar = t >> 2, ac = (t & 3) * 8;
  const int sr = t >> 2, sc = (t & 3) * 8;

  const u16* Ap = A + (size_t)(m0 + ar) * K_DIM + ac;
  const u16* Wp = W + (size_t)(n0 + sr) * K_DIM + sc;

  f32x4 acc[2][4];
#pragma unroll
  for (int i = 0; i < 2; ++i)
#pragma unroll
    for (int j = 0; j < 4; ++j) acc[i][j] = (f32x4){0.f, 0.f, 0.f, 0.f};

  uint4 ra = *(const uint4*)Ap;
  uint4 rb0 = *(const uint4*)(Wp);
  uint4 rb1 = *(const uint4*)(Wp + 64 * K_DIM);
  *(uint4*)&As[0][ar * LDA + ac] = ra;
  *(uint4*)&Bs[0][sr * LDA + sc] = rb0;
  *(uint4*)&Bs[0][(sr + 64) * LDA + sc] = rb1;
  ra = *(const uint4*)(Ap + 32);
  rb0 = *(const uint4*)(Wp + 32);
  rb1 = *(const uint4*)(Wp + 64 * K_DIM + 32);
  __syncthreads();

  for (int kt = 0; kt < 16; ++kt) {
    const int cur = kt & 1, nxt = cur ^ 1;
    if (kt < 15) {
      *(uint4*)&As[nxt][ar * LDA + ac] = ra;
      *(uint4*)&Bs[nxt][sr * LDA + sc] = rb0;
      *(uint4*)&Bs[nxt][(sr + 64) * LDA + sc] = rb1;
    }
    if (kt < 14) {
      int ko = (kt + 2) * 32;
      ra = *(const uint4*)(Ap + ko);
      rb0 = *(const uint4*)(Wp + ko);
      rb1 = *(const uint4*)(Wp + 64 * K_DIM + ko);
    }
    bf16x8 af[2], bfr[4];
#pragma unroll
    for (int mi = 0; mi < 2; ++mi)
      af[mi] = *(const bf16x8*)&As[cur][(wm + mi * 16 + l16) * LDA + quad * 8];
#pragma unroll
    for (int ni = 0; ni < 4; ++ni)
      bfr[ni] = *(const bf16x8*)&Bs[cur][(wn + ni * 16 + l16) * LDA + quad * 8];
#pragma unroll
    for (int mi = 0; mi < 2; ++mi)
#pragma unroll
      for (int ni = 0; ni < 4; ++ni)
        acc[mi][ni] = __builtin_amdgcn_mfma_f32_16x16x32_bf16(af[mi], bfr[ni], acc[mi][ni], 0, 0, 0);
    __syncthreads();
  }

#pragma unroll
  for (int ni = 0; ni < 4; ++ni) {
    int f = n0 + wn + ni * 16 + l16;
    float bv = bias[f];
#pragma unroll
    for (int mi = 0; mi < 2; ++mi)
#pragma unroll
      for (int r = 0; r < 4; ++r) {
        int m = m0 + wm + mi * 16 + quad * 4 + r;
        out[(size_t)m * 512 + f] = acc[mi][ni][r] + bv;
      }
  }
}

// ---------------- launcher ----------------
extern "C" void kernel_launch(void* const* d_in, const int* in_sizes, int n_in,
                              void* d_out, int out_size, void* d_ws, size_t ws_size,
                              hipStream_t stream) {
  const float* x1   = (const float*)d_in[0];
  const float* x2   = (const float*)d_in[1];
  const float* qkvw = (const float*)d_in[2];
  const float* qkvb = (const float*)d_in[3];
  const float* outw = (const float*)d_in[4];
  const float* outb = (const float*)d_in[5];
  float* out = (float*)d_out;
  char* ws = (char*)d_ws;

  u16* xb    = (u16*)(ws + 0);          // [8192][512] bf16
  u16* wqkv  = (u16*)(ws + 8388608);    // [1536][512]
  u16* wout  = (u16*)(ws + 9961472);    // [512][512]
  u16* qb    = (u16*)(ws + 10485760);   // [2][2][8][2048][64]
  u16* kb    = (u16*)(ws + 18874368);   // [2][2][8][2048][64]
  u16* vtb   = (u16*)(ws + 27262976);   // [2][2][8][64][2048]
  u16* attnb = (u16*)(ws + 0);          // [8192][512]  (aliases xb)

  cvt_kernel<<<5120, 256, 0, stream>>>(x1, x2, qkvw, outw, xb, wqkv, wout);

  dim3 g1(64, 12);
  qkv_gemm<<<g1, 256, 0, stream>>>(xb, wqkv, qkvb, qb, kb, vtb);

  attn_kernel<<<512, 256, 0, stream>>>(qb, kb, vtb, attnb);

  dim3 g3(128, 4);
  out_gemm<<<g3, 256, 0, stream>>>(attnb, wout, outb, out);
}

// Round 4
// 150.456 us; speedup vs baseline: 1.0667x; 1.0244x over previous
//
#include <hip/hip_runtime.h>
#include <stdint.h>

typedef unsigned short u16;
typedef unsigned int u32;
typedef short bf16x8 __attribute__((ext_vector_type(8)));
typedef float f32x4 __attribute__((ext_vector_type(4)));
typedef float f32x16 __attribute__((ext_vector_type(16)));

#define K_DIM 512

__device__ __forceinline__ u16 f2bf(float f) {
  union { float f; u32 u; } v; v.f = f;
  return (u16)((v.u + 0x8000u) >> 16);  // round-half-up
}
__device__ __forceinline__ u32 pk2(float lo, float hi) {
  union { float f; u32 u; } a, b; a.f = lo; b.f = hi;
  return __builtin_amdgcn_perm(b.u + 0x8000u, a.u + 0x8000u, 0x07060302u);
}

// ---------------- kernel 0: fp32 -> bf16 conversions ----------------
__global__ void cvt_kernel(const float* __restrict__ x1, const float* __restrict__ x2,
                           const float* __restrict__ qkvw, const float* __restrict__ outw,
                           u16* __restrict__ xb, u16* __restrict__ wqkv, u16* __restrict__ wout) {
  int tid = blockIdx.x * 256 + threadIdx.x;
  const float4* src; u16* dst; int idx = tid;
  if (idx < 524288)        { src = (const float4*)x1;   dst = xb; }
  else if (idx < 1048576)  { src = (const float4*)x2;   dst = xb + 2097152; idx -= 524288; }
  else if (idx < 1245184)  { src = (const float4*)qkvw; dst = wqkv;         idx -= 1048576; }
  else                     { src = (const float4*)outw; dst = wout;         idx -= 1245184; }
  float4 v = src[idx];
  *(uint2*)&dst[idx * 4] = make_uint2(pk2(v.x, v.y), pk2(v.z, v.w));
}

#define LDA 40  // BK=32 + 8 pad

// ---------------- kernel 1: QKV GEMM (C^T, dbuf single-barrier) + scatter epilogue ----------------
__global__ __launch_bounds__(256, 3) void qkv_gemm(
    const u16* __restrict__ A, const u16* __restrict__ W, const float* __restrict__ bias,
    u16* __restrict__ qb, u16* __restrict__ kb, u16* __restrict__ vtb) {
  __shared__ __align__(16) u16 As[2][128 * LDA];
  __shared__ __align__(16) u16 Bs[2][128 * LDA];
  const int t = threadIdx.x;
  const int m0 = blockIdx.x * 128, n0 = blockIdx.y * 128;
  const int lane = t & 63, l16 = lane & 15, quad = lane >> 4;
  const int w = t >> 6;
  const int wm = (w >> 1) * 64, wn = (w & 1) * 64;
  const int sr = t >> 2, sc = (t & 3) * 8;

  const u16* Ap = A + (size_t)(m0 + sr) * K_DIM + sc;
  const u16* Wp = W + (size_t)(n0 + sr) * K_DIM + sc;

  f32x4 acc[4][4];
#pragma unroll
  for (int i = 0; i < 4; ++i)
#pragma unroll
    for (int j = 0; j < 4; ++j) acc[i][j] = (f32x4){0.f, 0.f, 0.f, 0.f};

  uint4 ra0 = *(const uint4*)(Ap);
  uint4 ra1 = *(const uint4*)(Ap + 64 * K_DIM);
  uint4 rb0 = *(const uint4*)(Wp);
  uint4 rb1 = *(const uint4*)(Wp + 64 * K_DIM);
  *(uint4*)&As[0][sr * LDA + sc] = ra0;
  *(uint4*)&As[0][(sr + 64) * LDA + sc] = ra1;
  *(uint4*)&Bs[0][sr * LDA + sc] = rb0;
  *(uint4*)&Bs[0][(sr + 64) * LDA + sc] = rb1;
  ra0 = *(const uint4*)(Ap + 32);
  ra1 = *(const uint4*)(Ap + 64 * K_DIM + 32);
  rb0 = *(const uint4*)(Wp + 32);
  rb1 = *(const uint4*)(Wp + 64 * K_DIM + 32);
  __syncthreads();

  for (int kt = 0; kt < 16; ++kt) {
    const int cur = kt & 1, nxt = cur ^ 1;
    if (kt < 15) {
      *(uint4*)&As[nxt][sr * LDA + sc] = ra0;
      *(uint4*)&As[nxt][(sr + 64) * LDA + sc] = ra1;
      *(uint4*)&Bs[nxt][sr * LDA + sc] = rb0;
      *(uint4*)&Bs[nxt][(sr + 64) * LDA + sc] = rb1;
    }
    if (kt < 14) {
      int ko = (kt + 2) * 32;
      ra0 = *(const uint4*)(Ap + ko);
      ra1 = *(const uint4*)(Ap + 64 * K_DIM + ko);
      rb0 = *(const uint4*)(Wp + ko);
      rb1 = *(const uint4*)(Wp + 64 * K_DIM + ko);
    }
    bf16x8 af[4], bfr[4];
#pragma unroll
    for (int mi = 0; mi < 4; ++mi)
      af[mi] = *(const bf16x8*)&As[cur][(wm + mi * 16 + l16) * LDA + quad * 8];
#pragma unroll
    for (int ni = 0; ni < 4; ++ni)
      bfr[ni] = *(const bf16x8*)&Bs[cur][(wn + ni * 16 + l16) * LDA + quad * 8];
#pragma unroll
    for (int mi = 0; mi < 4; ++mi)
#pragma unroll
      for (int ni = 0; ni < 4; ++ni)
        acc[mi][ni] = __builtin_amdgcn_mfma_f32_16x16x32_bf16(bfr[ni], af[mi], acc[mi][ni], 0, 0, 0);
    __syncthreads();
  }

  const int fbase = n0 + wn;
  const int h = fbase / 192;
  const int s = (fbase - h * 192) >> 6;
  float4 bv[4];
#pragma unroll
  for (int ni = 0; ni < 4; ++ni)
    bv[ni] = *(const float4*)&bias[fbase + ni * 16 + quad * 4];
  const int bh = m0 >> 11;
  const int lbase = (m0 & 2047) + wm;

  if (s == 2) {
    u16* dst = vtb + (size_t)((bh * 8 + h) * 64) * 2048;
#pragma unroll
    for (int mi = 0; mi < 4; ++mi) {
      int l = lbase + mi * 16 + l16;
#pragma unroll
      for (int ni = 0; ni < 4; ++ni)
#pragma unroll
        for (int r = 0; r < 4; ++r)
          dst[(ni * 16 + quad * 4 + r) * 2048 + l] = f2bf(acc[mi][ni][r] + bv[ni][r]);
    }
  } else {
    u16* dst = (s == 0 ? qb : kb) + (size_t)((bh * 8 + h) * 2048) * 64;
    const float sc2 = (s == 0) ? 0.18033688011112042f : 1.0f;
#pragma unroll
    for (int mi = 0; mi < 4; ++mi) {
      int l = lbase + mi * 16 + l16;
#pragma unroll
      for (int ni = 0; ni < 4; ++ni) {
        float v0 = (acc[mi][ni][0] + bv[ni][0]) * sc2;
        float v1 = (acc[mi][ni][1] + bv[ni][1]) * sc2;
        float v2 = (acc[mi][ni][2] + bv[ni][2]) * sc2;
        float v3 = (acc[mi][ni][3] + bv[ni][3]) * sc2;
        *(uint2*)&dst[(size_t)l * 64 + ni * 16 + quad * 4] = make_uint2(pk2(v0, v1), pk2(v2, v3));
      }
    }
  }
}

// ---------------- kernel 2: flash cross-attention, T15 one-tile pipeline ----------------
// Per phase kt: issue S(kt) MFMAs (matrix pipe) -> softmax(kt-1) on VALU overlaps them ->
// PV(kt-1) MFMAs -> stage(kt+1) -> single barrier. K 2-ring, V 4-ring (PV lags one phase:
// stage(kt+1)&3 vs PV(kt-1)&3 always distinct; last reader of stage buffer was PV(kt-3),
// >=2 barriers ago). Two named sacc states (sA even kt, sB odd kt) keep indexing static.
// P stays in registers: exp2 -> pk2 (round-half-up; v_cvt_pk_bf16_f32 truncates on gfx950
// and failed verification at 5.4e-3) -> v_permlane32_swap_b32 (T12).
// Layouts (m101): C/D col=lane&31, row=(reg&3)+8*(reg>>2)+4*(lane>>5).
#define LQ 72

#define SPHASE(SS, KBUF)                                                          \
  do {                                                                            \
    _Pragma("unroll") for (int r_ = 0; r_ < 16; ++r_) {                           \
      SS[0][r_] = 0.f; SS[1][r_] = 0.f;                                           \
    }                                                                             \
    _Pragma("unroll") for (int ks_ = 0; ks_ < 4; ++ks_) {                         \
      bf16x8 kfr0 = *(const bf16x8*)&Ks[KBUF][l32 * LQ + ks_ * 16 + h2 * 8];      \
      bf16x8 kfr1 = *(const bf16x8*)&Ks[KBUF][(32 + l32) * LQ + ks_ * 16 + h2 * 8]; \
      SS[0] = __builtin_amdgcn_mfma_f32_32x32x16_bf16(kfr0, qf[ks_], SS[0], 0, 0, 0); \
      SS[1] = __builtin_amdgcn_mfma_f32_32x32x16_bf16(kfr1, qf[ks_], SS[1], 0, 0, 0); \
    }                                                                             \
  } while (0)

#define SOFTPV(SS, VBUF)                                                          \
  do {                                                                            \
    bf16x8 pf[4];                                                                 \
    _Pragma("unroll") for (int mi_ = 0; mi_ < 2; ++mi_) {                         \
      float p[16];                                                                \
      _Pragma("unroll") for (int r_ = 0; r_ < 16; ++r_)                           \
        p[r_] = __builtin_amdgcn_exp2f(SS[mi_][r_]);                              \
      _Pragma("unroll") for (int r_ = 0; r_ < 16; r_ += 4)                        \
        rs += (p[r_] + p[r_ + 1]) + (p[r_ + 2] + p[r_ + 3]);                      \
      u32 a0 = pk2(p[0], p[1]),   b0 = pk2(p[2], p[3]);                           \
      u32 c0 = pk2(p[4], p[5]),   d0 = pk2(p[6], p[7]);                           \
      u32 a1 = pk2(p[8], p[9]),   b1 = pk2(p[10], p[11]);                         \
      u32 c1 = pk2(p[12], p[13]), d1 = pk2(p[14], p[15]);                         \
      asm("v_permlane32_swap_b32 %0, %1" : "+v"(a0), "+v"(c0));                   \
      asm("v_permlane32_swap_b32 %0, %1" : "+v"(b0), "+v"(d0));                   \
      asm("v_permlane32_swap_b32 %0, %1" : "+v"(a1), "+v"(c1));                   \
      asm("v_permlane32_swap_b32 %0, %1" : "+v"(b1), "+v"(d1));                   \
      union { u32 u[4]; bf16x8 v; } f0_, f1_;                                     \
      f0_.u[0] = a0; f0_.u[1] = b0; f0_.u[2] = c0; f0_.u[3] = d0;                 \
      f1_.u[0] = a1; f1_.u[1] = b1; f1_.u[2] = c1; f1_.u[3] = d1;                 \
      pf[mi_ * 2] = f0_.v; pf[mi_ * 2 + 1] = f1_.v;                               \
    }                                                                             \
    const u16* vb_ = (const u16*)VTs + (VBUF) * (64 * LQ);                        \
    _Pragma("unroll") for (int ks_ = 0; ks_ < 4; ++ks_) {                         \
      bf16x8 vf0 = *(const bf16x8*)&vb_[l32 * LQ + ks_ * 16 + h2 * 8];            \
      bf16x8 vf1 = *(const bf16x8*)&vb_[(32 + l32) * LQ + ks_ * 16 + h2 * 8];     \
      oacc[0] = __builtin_amdgcn_mfma_f32_32x32x16_bf16(vf0, pf[ks_], oacc[0], 0, 0, 0); \
      oacc[1] = __builtin_amdgcn_mfma_f32_32x32x16_bf16(vf1, pf[ks_], oacc[1], 0, 0, 0); \
    }                                                                             \
  } while (0)

__global__ __launch_bounds__(256, 2) void attn_kernel(
    const u16* __restrict__ qb, const u16* __restrict__ kb, const u16* __restrict__ vtb,
    u16* __restrict__ attnb) {
  __shared__ __align__(16) u16 Ks[2][64 * LQ];
  __shared__ __align__(16) u16 VTs[4][64 * LQ];

  const int t = threadIdx.x;
  const int w = t >> 6, lane = t & 63, l32 = lane & 31, h2 = lane >> 5;
  const int bid = blockIdx.x;
  const int comb = bid & 31;        // XCD swizzle: same comb -> same bid%8 -> same XCD
  const int qt = bid >> 5;
  const int h = comb & 7, bb = (comb >> 3) & 1, pair = comb >> 4;
  const int in_q = pair, in_kv = pair ^ 1;

  const u16* Qg = qb + (size_t)((in_q * 2 + bb) * 8 + h) * 2048 * 64;
  const u16* Kg = kb + (size_t)((in_kv * 2 + bb) * 8 + h) * 2048 * 64;
  const u16* Vg = vtb + (size_t)((in_kv * 2 + bb) * 8 + h) * 64 * 2048;

  const int srow = t >> 3, sseg = (t & 7) * 8;   // rows 0..31 (+32)
  uint4 rk0 = *(const uint4*)(Kg + srow * 64 + sseg);
  uint4 rk1 = *(const uint4*)(Kg + (srow + 32) * 64 + sseg);
  uint4 rv0 = *(const uint4*)(Vg + srow * 2048 + sseg);
  uint4 rv1 = *(const uint4*)(Vg + (srow + 32) * 2048 + sseg);

  // Q fragments straight from global (16B aligned, read once, L2-resident)
  bf16x8 qf[4];
#pragma unroll
  for (int ks = 0; ks < 4; ++ks)
    qf[ks] = *(const bf16x8*)(Qg + (qt * 128 + w * 32 + l32) * 64 + ks * 16 + h2 * 8);

  auto stage = [&](int kbuf, int vbuf) {
    *(uint4*)&Ks[kbuf][srow * LQ + sseg] = rk0;
    *(uint4*)&Ks[kbuf][(srow + 32) * LQ + sseg] = rk1;
    *(uint4*)&VTs[vbuf][srow * LQ + sseg] = rv0;
    *(uint4*)&VTs[vbuf][(srow + 32) * LQ + sseg] = rv1;
  };
  auto gload = [&](int kt) {
    const int ko = kt * 64;
    rk0 = *(const uint4*)(Kg + (ko + srow) * 64 + sseg);
    rk1 = *(const uint4*)(Kg + (ko + srow + 32) * 64 + sseg);
    rv0 = *(const uint4*)(Vg + srow * 2048 + ko + sseg);
    rv1 = *(const uint4*)(Vg + (srow + 32) * 2048 + ko + sseg);
  };

  f32x16 oacc[2];
#pragma unroll
  for (int mi = 0; mi < 2; ++mi)
#pragma unroll
    for (int r = 0; r < 16; ++r) oacc[mi][r] = 0.f;
  float rs = 0.f;
  f32x16 sA[2], sB[2];

  // prologue: tile0 -> buf0; S(0); tile1 -> bufs 1; prefetch tile2
  stage(0, 0);
  gload(1);
  __syncthreads();              // tile 0 visible

  SPHASE(sA, 0);                // S(0)
  stage(1, 1);
  gload(2);
  __syncthreads();              // end of phase 0

#pragma unroll 1
  for (int it = 0; it < 16; ++it) {
    const int e = (it & 1) << 1;          // 0 or 2
    // ---- odd phase: kt = 2it+1 ----
    SPHASE(sB, 1);                        // S(kt), Ks[1]
    SOFTPV(sA, e);                        // softmax+PV(kt-1), VTs[(2it)&3]
    if (it == 15) break;                  // kt==31: no more tiles; epilogue below
    stage(0, e ^ 2);                      // tile kt+1 = 2it+2
    gload(2 * it + 3);                    // tile kt+2 (<=31 for it<=14)
    __syncthreads();
    // ---- even phase: kt = 2it+2 (<=30) ----
    SPHASE(sA, 0);                        // S(kt), Ks[0]
    SOFTPV(sB, e + 1);                    // softmax+PV(kt-1), VTs[(2it+1)&3]
    stage(1, e ^ 3);                      // tile kt+1 = 2it+3
    if (it < 14) gload(2 * it + 4);       // tile kt+2
    __syncthreads();
  }
  // epilogue phase: softmax+PV(31)
  SOFTPV(sB, 3);

  // epilogue: qrow = w*32 + l32 owned by lanes (l32, l32+32) with complementary kcol/d sets
  rs += __shfl_xor(rs, 32);
  const float inv = 1.0f / rs;
  const int row = in_q * 4096 + bb * 2048 + qt * 128 + w * 32 + l32;
#pragma unroll
  for (int mi = 0; mi < 2; ++mi)
#pragma unroll
    for (int rg = 0; rg < 4; ++rg) {
      float v0 = oacc[mi][rg * 4 + 0] * inv;
      float v1 = oacc[mi][rg * 4 + 1] * inv;
      float v2 = oacc[mi][rg * 4 + 2] * inv;
      float v3 = oacc[mi][rg * 4 + 3] * inv;
      *(uint2*)&attnb[(size_t)row * 512 + h * 64 + mi * 32 + rg * 8 + h2 * 4] =
          make_uint2(pk2(v0, v1), pk2(v2, v3));
    }
}

// ---------------- kernel 3: output projection (64x128 tiles, dbuf) ----------------
__global__ __launch_bounds__(256, 2) void out_gemm(
    const u16* __restrict__ A, const u16* __restrict__ W, const float* __restrict__ bias,
    float* __restrict__ out) {
  __shared__ __align__(16) u16 As[2][64 * LDA];
  __shared__ __align__(16) u16 Bs[2][128 * LDA];
  const int t = threadIdx.x;
  const int m0 = blockIdx.x * 64, n0 = blockIdx.y * 128;
  const int lane = t & 63, l16 = lane & 15, quad = lane >> 4;
  const int w = t >> 6;
  const int wm = (w & 1) * 32, wn = (w >> 1) * 64;
  const int ar = t >> 2, ac = (t & 3) * 8;
  const int sr = t >> 2, sc = (t & 3) * 8;

  const u16* Ap = A + (size_t)(m0 + ar) * K_DIM + ac;
  const u16* Wp = W + (size_t)(n0 + sr) * K_DIM + sc;

  f32x4 acc[2][4];
#pragma unroll
  for (int i = 0; i < 2; ++i)
#pragma unroll
    for (int j = 0; j < 4; ++j) acc[i][j] = (f32x4){0.f, 0.f, 0.f, 0.f};

  uint4 ra = *(const uint4*)Ap;
  uint4 rb0 = *(const uint4*)(Wp);
  uint4 rb1 = *(const uint4*)(Wp + 64 * K_DIM);
  *(uint4*)&As[0][ar * LDA + ac] = ra;
  *(uint4*)&Bs[0][sr * LDA + sc] = rb0;
  *(uint4*)&Bs[0][(sr + 64) * LDA + sc] = rb1;
  ra = *(const uint4*)(Ap + 32);
  rb0 = *(const uint4*)(Wp + 32);
  rb1 = *(const uint4*)(Wp + 64 * K_DIM + 32);
  __syncthreads();

  for (int kt = 0; kt < 16; ++kt) {
    const int cur = kt & 1, nxt = cur ^ 1;
    if (kt < 15) {
      *(uint4*)&As[nxt][ar * LDA + ac] = ra;
      *(uint4*)&Bs[nxt][sr * LDA + sc] = rb0;
      *(uint4*)&Bs[nxt][(sr + 64) * LDA + sc] = rb1;
    }
    if (kt < 14) {
      int ko = (kt + 2) * 32;
      ra = *(const uint4*)(Ap + ko);
      rb0 = *(const uint4*)(Wp + ko);
      rb1 = *(const uint4*)(Wp + 64 * K_DIM + ko);
    }
    bf16x8 af[2], bfr[4];
#pragma unroll
    for (int mi = 0; mi < 2; ++mi)
      af[mi] = *(const bf16x8*)&As[cur][(wm + mi * 16 + l16) * LDA + quad * 8];
#pragma unroll
    for (int ni = 0; ni < 4; ++ni)
      bfr[ni] = *(const bf16x8*)&Bs[cur][(wn + ni * 16 + l16) * LDA + quad * 8];
#pragma unroll
    for (int mi = 0; mi < 2; ++mi)
#pragma unroll
      for (int ni = 0; ni < 4; ++ni)
        acc[mi][ni] = __builtin_amdgcn_mfma_f32_16x16x32_bf16(af[mi], bfr[ni], acc[mi][ni], 0, 0, 0);
    __syncthreads();
  }

#pragma unroll
  for (int ni = 0; ni < 4; ++ni) {
    int f = n0 + wn + ni * 16 + l16;
    float bv = bias[f];
#pragma unroll
    for (int mi = 0; mi < 2; ++mi)
#pragma unroll
      for (int r = 0; r < 4; ++r) {
        int m = m0 + wm + mi * 16 + quad * 4 + r;
        out[(size_t)m * 512 + f] = acc[mi][ni][r] + bv;
      }
  }
}

// ---------------- launcher ----------------
extern "C" void kernel_launch(void* const* d_in, const int* in_sizes, int n_in,
                              void* d_out, int out_size, void* d_ws, size_t ws_size,
                              hipStream_t stream) {
  const float* x1   = (const float*)d_in[0];
  const float* x2   = (const float*)d_in[1];
  const float* qkvw = (const float*)d_in[2];
  const float* qkvb = (const float*)d_in[3];
  const float* outw = (const float*)d_in[4];
  const float* outb = (const float*)d_in[5];
  float* out = (float*)d_out;
  char* ws = (char*)d_ws;

  u16* xb    = (u16*)(ws + 0);          // [8192][512] bf16
  u16* wqkv  = (u16*)(ws + 8388608);    // [1536][512]
  u16* wout  = (u16*)(ws + 9961472);    // [512][512]
  u16* qb    = (u16*)(ws + 10485760);   // [2][2][8][2048][64]
  u16* kb    = (u16*)(ws + 18874368);   // [2][2][8][2048][64]
  u16* vtb   = (u16*)(ws + 27262976);   // [2][2][8][64][2048]
  u16* attnb = (u16*)(ws + 0);          // [8192][512]  (aliases xb)

  cvt_kernel<<<5120, 256, 0, stream>>>(x1, x2, qkvw, outw, xb, wqkv, wout);

  dim3 g1(64, 12);
  qkv_gemm<<<g1, 256, 0, stream>>>(xb, wqkv, qkvb, qb, kb, vtb);

  attn_kernel<<<512, 256, 0, stream>>>(qb, kb, vtb, attnb);

  dim3 g3(128, 4);
  out_gemm<<<g3, 256, 0, stream>>>(attnb, wout, outb, out);
}